// Round 14
// baseline (236.563 us; speedup 1.0000x reference)
//
#include <hip/hip_runtime.h>

#define N_PTS   30000
#define M_ATOMS 8000
#define D       16
#define KNN     16
#define NGRP    125           // 8000 / 64 exactly
#define EPS     1e-5f
#define SLOPE   0.2f
#define BN_COUNT 480000.0f    // N_PTS * KNN

typedef unsigned long long ull;

__device__ __forceinline__ float leaky(float x) { return x > 0.f ? x : SLOPE * x; }

// sortable key: strictly monotone bijection float -> u32 (and inverse)
__device__ __forceinline__ unsigned fkey(float f) {
  unsigned u = __float_as_uint(f);
  return u ^ ((u & 0x80000000u) ? 0xFFFFFFFFu : 0x80000000u);
}
__device__ __forceinline__ float unfkey(unsigned e) {
  unsigned u = (e & 0x80000000u) ? (e ^ 0x80000000u) : ~e;
  return __uint_as_float(u);
}

// ---- DPP wave reductions (row_shr:1/2/4/8 -> bcast15 -> bcast31 -> lane63)
#define DPPSTEP32(v, CTRL) {                                                   \
  unsigned t_ = (unsigned)__builtin_amdgcn_update_dpp(-1, (int)(v), CTRL, 0xF, 0xF, false); \
  (v) = t_ < (v) ? t_ : (v); }

__device__ __forceinline__ unsigned wmin32d(unsigned v) {
  DPPSTEP32(v, 0x111); DPPSTEP32(v, 0x112); DPPSTEP32(v, 0x114);
  DPPSTEP32(v, 0x118); DPPSTEP32(v, 0x142); DPPSTEP32(v, 0x143);
  return (unsigned)__builtin_amdgcn_readlane((int)v, 63);   // wave-uniform
}

// u64 wave-max; out-of-range DPP lanes supply 0 (safe sentinel for max:
// real keys have fkey(d2) top bits set, never 0)
#define DPPSTEP64MAX(lo, hi, CTRL) {                                           \
  unsigned tlo_ = (unsigned)__builtin_amdgcn_update_dpp(0, (int)(lo), CTRL, 0xF, 0xF, false); \
  unsigned thi_ = (unsigned)__builtin_amdgcn_update_dpp(0, (int)(hi), CTRL, 0xF, 0xF, false); \
  bool gt_ = (thi_ > (hi)) || ((thi_ == (hi)) && (tlo_ > (lo)));               \
  (lo) = gt_ ? tlo_ : (lo); (hi) = gt_ ? thi_ : (hi); }

__device__ __forceinline__ ull wmax64d(ull v) {
  unsigned lo = (unsigned)v, hi = (unsigned)(v >> 32);
  DPPSTEP64MAX(lo, hi, 0x111); DPPSTEP64MAX(lo, hi, 0x112);
  DPPSTEP64MAX(lo, hi, 0x114); DPPSTEP64MAX(lo, hi, 0x118);
  DPPSTEP64MAX(lo, hi, 0x142); DPPSTEP64MAX(lo, hi, 0x143);
  unsigned flo = (unsigned)__builtin_amdgcn_readlane((int)lo, 63);
  unsigned fhi = (unsigned)__builtin_amdgcn_readlane((int)hi, 63);
  return ((ull)fhi << 32) | flo;
}

__device__ __forceinline__ int morton_cell(float x, float y, float z) {
  int cx = min(max((int)floorf((x + 4.f) * 2.f), 0), 15);
  int cy = min(max((int)floorf((y + 4.f) * 2.f), 0), 15);
  int cz = min(max((int)floorf((z + 4.f) * 2.f), 0), 15);
  int c = 0;
#pragma unroll
  for (int b = 0; b < 4; ++b)
    c |= (((cx>>b)&1) << (3*b)) | (((cy>>b)&1) << (3*b+1)) | (((cz>>b)&1) << (3*b+2));
  return c;
}

// ---------------------------------------------------------------------------
// KB: one-block prep head (proven R13). LDS Morton histogram -> scan ->
// cursors; zeros gstats; inits encoded bounds.
// ---------------------------------------------------------------------------
__global__ void __launch_bounds__(1024) kB_hist_scan(
    const float* __restrict__ atom_xyz, int* __restrict__ cursors,
    float* __restrict__ gstats, unsigned* __restrict__ benc) {
  __shared__ int h0[4096], h1[4096];
  int tid = threadIdx.x;
  for (int i = tid; i < 4096; i += 1024) h0[i] = 0;
  if (tid < 288) gstats[tid] = 0.f;
  if (tid >= 288 && tid < 663) benc[tid - 288] = 0xFFFFFFFFu;    // mins [0,375)
  if (tid >= 663 && tid < 1024) benc[tid - 288] = 0u;            // maxes [375,736)
  if (tid < 14) benc[736 + tid] = 0u;                            // maxes tail
  __syncthreads();
  for (int m = tid; m < M_ATOMS; m += 1024) {
    int c = morton_cell(atom_xyz[m*3], atom_xyz[m*3+1], atom_xyz[m*3+2]);
    atomicAdd(&h0[c], 1);
  }
  __syncthreads();
  int* src = h0; int* dst = h1;
  for (int off = 1; off < 4096; off <<= 1) {
    for (int i = tid; i < 4096; i += 1024) {
      int v = src[i];
      if (i >= off) v += src[i-off];
      dst[i] = v;
    }
    __syncthreads();
    int* t = src; src = dst; dst = t;
  }
  for (int i = tid; i < 4096; i += 1024) cursors[i] = i ? src[i-1] : 0;
}

// ---------------------------------------------------------------------------
// KC: fused scatter (cursor atomics + encoded AABB atomics) + atom MLP -> u'
// (proven R13)
// ---------------------------------------------------------------------------
#define LAYER(IN, OUT, W, B)                                        \
  _Pragma("unroll") for (int j = 0; j < 16; ++j) {                  \
    float acc = B[j];                                               \
    _Pragma("unroll") for (int i = 0; i < 16; ++i)                  \
      acc = fmaf(IN[i], W[i*16+j], acc);                            \
    OUT[j] = leaky(acc);                                            \
  }

__global__ void __launch_bounds__(256) kC_scatter_mlp(
    const float* __restrict__ atom_xyz, const float* __restrict__ atom_types,
    const float* __restrict__ Wt1, const float* __restrict__ bt1,
    const float* __restrict__ Wt2, const float* __restrict__ bt2,
    const float* __restrict__ Wt3, const float* __restrict__ bt3,
    const float* __restrict__ W1, const float* __restrict__ b1,
    int* __restrict__ cursors, float4* __restrict__ atoms4s,
    int* __restrict__ origid, unsigned* __restrict__ benc,
    float* __restrict__ tu_out) {
  __shared__ float w1[256], w2[256], w3[256], wc[256];
  __shared__ float bb1[16], bb2[16], bb3[16], bbc[16];
  int tid = threadIdx.x;
  w1[tid] = Wt1[tid]; w2[tid] = Wt2[tid]; w3[tid] = Wt3[tid]; wc[tid] = W1[tid];
  if (tid < 16) { bb1[tid] = bt1[tid]; bb2[tid] = bt2[tid];
                  bb3[tid] = bt3[tid]; bbc[tid] = b1[tid]; }
  __syncthreads();
  int m = blockIdx.x * 256 + tid;
  if (m >= M_ATOMS) return;

  float x = atom_xyz[m*3], y = atom_xyz[m*3+1], z = atom_xyz[m*3+2];
  int c = morton_cell(x, y, z);
  int pos = atomicAdd(&cursors[c], 1);
  atoms4s[pos] = make_float4(x, y, z, fmaf(x,x, fmaf(y,y, z*z)));
  origid[pos] = m;
  int g = pos >> 6;
  atomicMin(&benc[g],       fkey(x)); atomicMax(&benc[375+g], fkey(x));
  atomicMin(&benc[125+g],   fkey(y)); atomicMax(&benc[500+g], fkey(y));
  atomicMin(&benc[250+g],   fkey(z)); atomicMax(&benc[625+g], fkey(z));

  float u[16], v[16];
  const float4* tp = (const float4*)(atom_types + (size_t)m*16);
  float4 q0 = tp[0], q1 = tp[1], q2 = tp[2], q3 = tp[3];
  u[0]=q0.x; u[1]=q0.y; u[2]=q0.z; u[3]=q0.w;
  u[4]=q1.x; u[5]=q1.y; u[6]=q1.z; u[7]=q1.w;
  u[8]=q2.x; u[9]=q2.y; u[10]=q2.z; u[11]=q2.w;
  u[12]=q3.x; u[13]=q3.y; u[14]=q3.z; u[15]=q3.w;
  LAYER(u, v, w1, bb1);
  LAYER(v, u, w2, bb2);
  LAYER(u, v, w3, bb3);
  float up[16];
#pragma unroll
  for (int j = 0; j < 16; ++j) {
    float acc = bbc[j];
#pragma unroll
    for (int i = 0; i < 16; ++i) acc = fmaf(v[i], wc[i*16+j], acc);
    up[j] = acc;
  }
  float4* op = (float4*)(tu_out + (size_t)m*16);
  op[0] = make_float4(up[0], up[1], up[2], up[3]);
  op[1] = make_float4(up[4], up[5], up[6], up[7]);
  op[2] = make_float4(up[8], up[9], up[10], up[11]);
  op[3] = make_float4(up[12], up[13], up[14], up[15]);
}

// ---------------------------------------------------------------------------
// K2 v9: exact 16-NN + fused BN1 stats. Initial selection over 4 nearest
// groups (256 atoms, 4 keys/lane) via RADIX-SELECT of the exact 16th-smallest
// u64 key T (32-probe fkey search; rare fkey-tie -> idx-level search), then
// ballot-prefix compaction of {key <= T} (exactly 16, keys unique) to one
// key per lane. Residual groups: proven pop loop + max-evict insert.
// Downstream is sum-pooled, so set order is irrelevant.
// ---------------------------------------------------------------------------
__global__ void __launch_bounds__(256) k2_knn(
    const float* __restrict__ xyz, const float4* __restrict__ atoms4s,
    const int* __restrict__ origid, const unsigned* __restrict__ benc,
    const float* __restrict__ atom_xyz, const float* __restrict__ tu,
    const float* __restrict__ W1,
    int2* __restrict__ pairs, float* __restrict__ gstats) {
  __shared__ float sbuf[4*16*20 + 128];      // rows + per-wave select scratch
  int tid = threadIdx.x;
  int lane = tid & 63;
  int wid = tid >> 6;
  int n = blockIdx.x * 4 + wid;              // 30000 = 7500*4 exactly

  float px = xyz[n*3+0], py = xyz[n*3+1], pz = xyz[n*3+2];
  float x2 = fmaf(px,px, fmaf(py,py, pz*pz));

  // ---- group lower-bound keys (bounds decoded inline from benc) ----
  unsigned ea, eb = 0xFFFFFFFFu;
  {
    int g = lane;
    float mnx = unfkey(benc[g]),     mny = unfkey(benc[125+g]), mnz = unfkey(benc[250+g]);
    float mxx = unfkey(benc[375+g]), mxy = unfkey(benc[500+g]), mxz = unfkey(benc[625+g]);
    float dx = fmaxf(fmaxf(mnx - px, px - mxx), 0.f);
    float dy = fmaxf(fmaxf(mny - py, py - mxy), 0.f);
    float dz = fmaxf(fmaxf(mnz - pz, pz - mxz), 0.f);
    float lb = fmaf(dx,dx, fmaf(dy,dy, dz*dz)) * 0.999f - 1e-4f;
    ea = (fkey(lb) & 0xFFFFFF00u) | (unsigned)g;
  }
  if (lane + 64 < NGRP) {
    int g = lane + 64;
    float mnx = unfkey(benc[g]),     mny = unfkey(benc[125+g]), mnz = unfkey(benc[250+g]);
    float mxx = unfkey(benc[375+g]), mxy = unfkey(benc[500+g]), mxz = unfkey(benc[625+g]);
    float dx = fmaxf(fmaxf(mnx - px, px - mxx), 0.f);
    float dy = fmaxf(fmaxf(mny - py, py - mxy), 0.f);
    float dz = fmaxf(fmaxf(mnz - pz, pz - mxz), 0.f);
    float lb = fmaf(dx,dx, fmaf(dy,dy, dz*dz)) * 0.999f - 1e-4f;
    eb = (fkey(lb) & 0xFFFFFF00u) | (unsigned)g;
  }
  unsigned cur = ea < eb ? ea : eb;
  unsigned bak = ea < eb ? eb : ea;

  // ---- pop the 4 nearest groups ----
  int gs[4];
#pragma unroll
  for (int r = 0; r < 4; ++r) {
    unsigned m = wmin32d(cur);
    bool own = (cur == m);
    cur = own ? bak : cur;
    bak = own ? 0xFFFFFFFFu : bak;
    gs[r] = (int)(m & 0xFFu);
  }

  // ---- 4 atoms/lane -> (fkey, idx) keys, unsorted ----
  float4 A[4]; int OI[4];
#pragma unroll
  for (int r = 0; r < 4; ++r) {
    int base = gs[r] << 6;
    A[r]  = atoms4s[base + lane];
    OI[r] = origid [base + lane];
  }
  unsigned cf0, cf1, cf2, cf3, ci0, ci1, ci2, ci3;
  {
    float d0 = (x2 + A[0].w) - 2.f*fmaf(px,A[0].x, fmaf(py,A[0].y, pz*A[0].z));
    float d1 = (x2 + A[1].w) - 2.f*fmaf(px,A[1].x, fmaf(py,A[1].y, pz*A[1].z));
    float d2 = (x2 + A[2].w) - 2.f*fmaf(px,A[2].x, fmaf(py,A[2].y, pz*A[2].z));
    float d3 = (x2 + A[3].w) - 2.f*fmaf(px,A[3].x, fmaf(py,A[3].y, pz*A[3].z));
    cf0 = fkey(d0); cf1 = fkey(d1); cf2 = fkey(d2); cf3 = fkey(d3);
    ci0 = (unsigned)OI[0]; ci1 = (unsigned)OI[1];
    ci2 = (unsigned)OI[2]; ci3 = (unsigned)OI[3];
  }

  // ---- radix-select exact 16th-smallest (F on fkey; tie -> idx search) ----
  unsigned F = 0;
  for (int b = 31; b >= 0; --b) {
    unsigned x = F | (1u << b);
    int c = __popcll(__ballot(cf0 < x)) + __popcll(__ballot(cf1 < x))
          + __popcll(__ballot(cf2 < x)) + __popcll(__ballot(cf3 < x));
    if (c < KNN) F = x;
  }
  ull m0 = __ballot(cf0 == F), m1 = __ballot(cf1 == F);
  ull m2 = __ballot(cf2 == F), m3 = __ballot(cf3 == F);
  int c_eq = __popcll(m0) + __popcll(m1) + __popcll(m2) + __popcll(m3);
  unsigned I;
  if (c_eq == 1) {                           // common case: unique boundary fkey
    if (m0)      I = (unsigned)__builtin_amdgcn_readlane((int)ci0, (int)(__ffsll(m0)-1));
    else if (m1) I = (unsigned)__builtin_amdgcn_readlane((int)ci1, (int)(__ffsll(m1)-1));
    else if (m2) I = (unsigned)__builtin_amdgcn_readlane((int)ci2, (int)(__ffsll(m2)-1));
    else         I = (unsigned)__builtin_amdgcn_readlane((int)ci3, (int)(__ffsll(m3)-1));
  } else {                                   // rare: j-th smallest idx in eq-class
    int c_lt = __popcll(__ballot(cf0 < F)) + __popcll(__ballot(cf1 < F))
             + __popcll(__ballot(cf2 < F)) + __popcll(__ballot(cf3 < F));
    int j = KNN - c_lt;
    unsigned P = 0;
    for (int b = 31; b >= 0; --b) {
      unsigned x = P | (1u << b);
      int c = __popcll(__ballot(cf0 == F && ci0 < x))
            + __popcll(__ballot(cf1 == F && ci1 < x))
            + __popcll(__ballot(cf2 == F && ci2 < x))
            + __popcll(__ballot(cf3 == F && ci3 < x));
      if (c < j) P = x;
    }
    I = P;
  }
  ull T = ((ull)F << 32) | I;                // exact 16th-smallest u64 key

  // ---- compact {key <= T} (exactly 16) -> one key per lane 0..15 ----
  {
    unsigned* scr = (unsigned*)&sbuf[4*16*20 + wid*32];
    ull E0 = ((ull)cf0 << 32) | ci0, E1 = ((ull)cf1 << 32) | ci1;
    ull E2 = ((ull)cf2 << 32) | ci2, E3 = ((ull)cf3 << 32) | ci3;
    bool s0 = E0 <= T, s1 = E1 <= T, s2 = E2 <= T, s3 = E3 <= T;
    ull b0 = __ballot(s0), b1 = __ballot(s1), b2 = __ballot(s2), b3 = __ballot(s3);
    ull below = (lane == 63) ? 0x7FFFFFFFFFFFFFFFull : ((1ull << lane) - 1ull);
    int n0 = __popcll(b0), n1 = __popcll(b1), n2 = __popcll(b2);
    if (s0) { int p = __popcll(b0 & below);           scr[p] = cf0; scr[16+p] = ci0; }
    if (s1) { int p = n0 + __popcll(b1 & below);      scr[p] = cf1; scr[16+p] = ci1; }
    if (s2) { int p = n0+n1 + __popcll(b2 & below);   scr[p] = cf2; scr[16+p] = ci2; }
    if (s3) { int p = n0+n1+n2 + __popcll(b3 & below);scr[p] = cf3; scr[16+p] = ci3; }
  }
  ull lv = 0;                                // sentinel 0 (real keys >> 0)
  {
    unsigned* scr = (unsigned*)&sbuf[4*16*20 + wid*32];
    if (lane < KNN) lv = ((ull)scr[lane] << 32) | scr[16+lane];
  }
  ull thresh = T;

  // ---- residual groups: pop while lb < thresh; insert = max-evict ----
  for (int it = 0; it < NGRP - 4; ++it) {
    unsigned m = wmin32d(cur);
    if ((m & 0xFFFFFF00u) >= (unsigned)(thresh >> 32)) break;
    bool own = (cur == m);
    cur = own ? bak : cur;
    bak = own ? 0xFFFFFFFFu : bak;
    int base = (int)(m & 0xFFu) << 6;

    float4 a = atoms4s[base + lane];
    int oi2 = origid[base + lane];
    float dotp = fmaf(px,a.x, fmaf(py,a.y, pz*a.z));
    float d2 = (x2 + a.w) - 2.f*dotp;
    ull key = ((ull)fkey(d2) << 32) | (unsigned)oi2;

    ull mk = __ballot(key < thresh);
    while (mk) {
      int src = (int)(__ffsll(mk) - 1);      // wave-uniform
      mk &= mk - 1;
      unsigned klo = (unsigned)__builtin_amdgcn_readlane((int)(unsigned)key, src);
      unsigned khi = (unsigned)__builtin_amdgcn_readlane((int)(unsigned)(key >> 32), src);
      ull kc = ((ull)khi << 32) | klo;
      if (kc < thresh) {
        // evict current max (exactly one lane holds it; keys unique, lanes>=16 hold 0)
        ull ball2 = __ballot(lv == thresh);
        int vl = (int)(__ffsll(ball2) - 1);
        if (lane == vl) lv = kc;
        thresh = wmax64d(lv);                // new 16th-best
      }
    }
  }

  // ---- epilogue: write pairs + fused BN1 stats (proven) ----
  int oi = (int)(unsigned)(lv & 0xFFFFFFFFull);
  float iv = 0.f;
  if (lane < KNN) {
    float bx = atom_xyz[oi*3+0], by = atom_xyz[oi*3+1], bz = atom_xyz[oi*3+2];
    float dx = px - bx, dy = py - by, dz = pz - bz;
    float dd = fmaf(dx,dx, fmaf(dy,dy, dz*dz));    // exact recompute (reference)
    iv = 1.f / dd;
    pairs[n*KNN + lane] = make_int2(oi, __float_as_int(iv));

    const float4* up4 = (const float4*)(tu + (size_t)oi*16);
    float4 u0 = up4[0], u1 = up4[1], u2 = up4[2], u3 = up4[3];
    float4* row = (float4*)&sbuf[(wid*16 + lane)*20];
    float4 w;
    w.x = leaky(fmaf(iv, W1[256+ 0], u0.x)); w.y = leaky(fmaf(iv, W1[256+ 1], u0.y));
    w.z = leaky(fmaf(iv, W1[256+ 2], u0.z)); w.w = leaky(fmaf(iv, W1[256+ 3], u0.w));
    row[0] = w;
    w.x = leaky(fmaf(iv, W1[256+ 4], u1.x)); w.y = leaky(fmaf(iv, W1[256+ 5], u1.y));
    w.z = leaky(fmaf(iv, W1[256+ 6], u1.z)); w.w = leaky(fmaf(iv, W1[256+ 7], u1.w));
    row[1] = w;
    w.x = leaky(fmaf(iv, W1[256+ 8], u2.x)); w.y = leaky(fmaf(iv, W1[256+ 9], u2.y));
    w.z = leaky(fmaf(iv, W1[256+10], u2.z)); w.w = leaky(fmaf(iv, W1[256+11], u2.w));
    row[2] = w;
    w.x = leaky(fmaf(iv, W1[256+12], u3.x)); w.y = leaky(fmaf(iv, W1[256+13], u3.y));
    w.z = leaky(fmaf(iv, W1[256+14], u3.z)); w.w = leaky(fmaf(iv, W1[256+15], u3.w));
    row[3] = w;
  }
  __syncthreads();
  // transpose-reduce 64 rows x 16 ch: thread = (grp, ch), 4 rows each
  {
    int ch = tid & 15, grp = tid >> 4;
    float S = 0.f, Q = 0.f;
#pragma unroll
    for (int i = 0; i < 4; ++i) {
      float v = sbuf[(grp*4 + i)*20 + ch];
      S += v; Q += v*v;
    }
    __syncthreads();                          // all reads done before overwrite
    sbuf[grp*20 + ch] = S;
    sbuf[400 + grp*20 + ch] = Q;
  }
  __syncthreads();
  if (tid < 32) {
    int ch = tid & 15;
    int off = (tid < 16) ? 0 : 400;
    float s = 0.f;
#pragma unroll
    for (int g = 0; g < 16; ++g) s += sbuf[off + g*20 + ch];
    atomicAdd(&gstats[(blockIdx.x & 7)*32 + tid], s);
  }
}

// ---------------------------------------------------------------------------
// a1 row from precomputed u': a1 = leaky(u'[idx] + iv * wiv)
// ---------------------------------------------------------------------------
__device__ __forceinline__ void a1_row(const float* __restrict__ tu, int idx,
                                       float iv, const float* wiv, float* a) {
  const float4* up = (const float4*)(tu + (size_t)idx*16);
  float4 r0 = up[0], r1 = up[1], r2 = up[2], r3 = up[3];
  float u[16];
  u[0]=r0.x; u[1]=r0.y; u[2]=r0.z; u[3]=r0.w;
  u[4]=r1.x; u[5]=r1.y; u[6]=r1.z; u[7]=r1.w;
  u[8]=r2.x; u[9]=r2.y; u[10]=r2.z; u[11]=r2.w;
  u[12]=r3.x; u[13]=r3.y; u[14]=r3.z; u[15]=r3.w;
#pragma unroll
  for (int j = 0; j < 16; ++j) a[j] = leaky(fmaf(iv, wiv[j], u[j]));
}

// ---------------------------------------------------------------------------
// K4 (byte-identical to R13): a1, BN1 -> h, fx1; a2, s2; BN2 stats.
// ---------------------------------------------------------------------------
__global__ void __launch_bounds__(256, 4) k4_main(
    const int2* __restrict__ pairs, const float* __restrict__ tu,
    const float* __restrict__ W1,
    const float* __restrict__ W2, const float* __restrict__ b2,
    const float* __restrict__ g1, const float* __restrict__ be1,
    float* __restrict__ fx1_out, float* __restrict__ s2_out,
    float* __restrict__ gstats) {
  __shared__ float wiv[16], w2s[256], b2s[16];
  __shared__ float sc1[16], sh1[16];
  __shared__ float buf[16*16*17];
  int tid = threadIdx.x;
  w2s[tid] = W2[tid];
  if (tid < 16) { wiv[tid] = W1[256 + tid]; b2s[tid] = b2[tid]; }
  if (tid < 16) {
    float s1 = 0.f, q1 = 0.f;
#pragma unroll
    for (int c = 0; c < 8; ++c) { s1 += gstats[c*32 + tid]; q1 += gstats[c*32 + 16 + tid]; }
    float mean = s1 * (1.f/BN_COUNT);
    float var  = q1 * (1.f/BN_COUNT) - mean*mean;
    float sC = g1[tid] / sqrtf(var + EPS);
    sc1[tid] = sC;
    sh1[tid] = be1[tid] - mean * sC;
  }
  __syncthreads();

  int g = blockIdx.x * 256 + tid;
  int p = tid >> 4, k = tid & 15;
  int2 pr = pairs[g];
  int idx = pr.x;
  float iv = __int_as_float(pr.y);
  float h[16], a2[16];
  a1_row(tu, idx, iv, wiv, h);
#pragma unroll
  for (int j = 0; j < 16; ++j) h[j] = fmaf(h[j], sc1[j], sh1[j]);
#pragma unroll
  for (int j = 0; j < 16; ++j) {
    float accj = b2s[j];
#pragma unroll
    for (int i = 0; i < 16; ++i) accj = fmaf(h[i], w2s[i*16+j], accj);
    a2[j] = leaky(accj);
  }

  float* myrow = &buf[(p*16 + k)*17];
  int p2 = tid >> 4, j2 = tid & 15;
#pragma unroll
  for (int j = 0; j < 16; ++j) myrow[j] = h[j];
  __syncthreads();
  {
    float s = 0.f;
#pragma unroll
    for (int kk = 0; kk < 16; ++kk) s += buf[(p2*16+kk)*17 + j2];
    fx1_out[(size_t)blockIdx.x*256 + tid] = s;
  }
  __syncthreads();
#pragma unroll
  for (int j = 0; j < 16; ++j) myrow[j] = a2[j];
  __syncthreads();
  float s2v = 0.f;
#pragma unroll
  for (int kk = 0; kk < 16; ++kk) s2v += buf[(p2*16+kk)*17 + j2];
  s2_out[(size_t)blockIdx.x*256 + tid] = s2v;
  __syncthreads();
#pragma unroll
  for (int j = 0; j < 16; ++j) myrow[j] = a2[j]*a2[j];
  __syncthreads();
  float q2v = 0.f;
#pragma unroll
  for (int kk = 0; kk < 16; ++kk) q2v += buf[(p2*16+kk)*17 + j2];
  __syncthreads();
  buf[p2*17 + j2] = s2v;
  buf[289 + p2*17 + j2] = q2v;
  __syncthreads();
  if (tid < 16) {
    float t1 = 0.f, t2 = 0.f;
#pragma unroll
    for (int pp = 0; pp < 16; ++pp) { t1 += buf[pp*17 + tid]; t2 += buf[289 + pp*17 + tid]; }
    atomicAdd(&gstats[256 + tid], t1);
    atomicAdd(&gstats[272 + tid], t2);
  }
}

// ---------------------------------------------------------------------------
// K5 (byte-identical to R13): fx2 = sc2*s2 + 16*sh2 ; out = [fx1,fx2]@W3 + b3
// ---------------------------------------------------------------------------
__global__ void __launch_bounds__(256) k5_final(
    const float* __restrict__ fx1_in, const float* __restrict__ s2_in,
    const float* __restrict__ gstats,
    const float* __restrict__ W3, const float* __restrict__ b3,
    const float* __restrict__ g2, const float* __restrict__ be2,
    float* __restrict__ out) {
  __shared__ float w[512], bb[16], sc2[16], sh2[16];
  int tid = threadIdx.x;
  w[tid] = W3[tid]; w[256+tid] = W3[256+tid];
  if (tid < 16) {
    bb[tid] = b3[tid];
    float mean = gstats[256+tid] * (1.f/BN_COUNT);
    float var  = gstats[272+tid] * (1.f/BN_COUNT) - mean*mean;
    float s = g2[tid] / sqrtf(var + EPS);
    sc2[tid] = s;
    sh2[tid] = be2[tid] - mean * s;
  }
  __syncthreads();
  int n = blockIdx.x * 256 + tid;
  if (n >= N_PTS) return;

  const float4* f1p = (const float4*)(fx1_in + (size_t)n*16);
  const float4* f2p = (const float4*)(s2_in  + (size_t)n*16);
  float4 x0=f1p[0], x1=f1p[1], x2=f1p[2], x3=f1p[3];
  float4 y0=f2p[0], y1=f2p[1], y2=f2p[2], y3=f2p[3];
  float f1[16] = {x0.x,x0.y,x0.z,x0.w, x1.x,x1.y,x1.z,x1.w,
                  x2.x,x2.y,x2.z,x2.w, x3.x,x3.y,x3.z,x3.w};
  float f2[16] = {y0.x,y0.y,y0.z,y0.w, y1.x,y1.y,y1.z,y1.w,
                  y2.x,y2.y,y2.z,y2.w, y3.x,y3.y,y3.z,y3.w};
#pragma unroll
  for (int i = 0; i < 16; ++i) f2[i] = fmaf(sc2[i], f2[i], 16.f * sh2[i]);

  float4* op = (float4*)(out + (size_t)n*16);
  float o[16];
#pragma unroll
  for (int j = 0; j < 16; ++j) {
    float accj = bb[j];
#pragma unroll
    for (int i = 0; i < 16; ++i) accj = fmaf(f1[i], w[i*16+j], accj);
#pragma unroll
    for (int i = 0; i < 16; ++i) accj = fmaf(f2[i], w[(16+i)*16+j], accj);
    o[j] = accj;
  }
  op[0] = make_float4(o[0], o[1], o[2], o[3]);
  op[1] = make_float4(o[4], o[5], o[6], o[7]);
  op[2] = make_float4(o[8], o[9], o[10], o[11]);
  op[3] = make_float4(o[12], o[13], o[14], o[15]);
}

// ---------------------------------------------------------------------------
extern "C" void kernel_launch(void* const* d_in, const int* in_sizes, int n_in,
                              void* d_out, int out_size, void* d_ws, size_t ws_size,
                              hipStream_t stream) {
  const float* xyz        = (const float*)d_in[0];
  const float* atom_xyz   = (const float*)d_in[1];
  const float* atom_types = (const float*)d_in[2];
  const float* Wt1 = (const float*)d_in[3];  const float* bt1 = (const float*)d_in[4];
  const float* Wt2 = (const float*)d_in[5];  const float* bt2 = (const float*)d_in[6];
  const float* Wt3 = (const float*)d_in[7];  const float* bt3 = (const float*)d_in[8];
  const float* W1  = (const float*)d_in[9];  const float* b1  = (const float*)d_in[10];
  const float* W2  = (const float*)d_in[11]; const float* b2  = (const float*)d_in[12];
  const float* W3  = (const float*)d_in[13]; const float* b3  = (const float*)d_in[14];
  const float* g1  = (const float*)d_in[15]; const float* be1 = (const float*)d_in[16];
  const float* g2  = (const float*)d_in[17]; const float* be2 = (const float*)d_in[18];
  float* out = (float*)d_out;

  float* ws = (float*)d_ws;
  float*    tu      = ws;                          // 8000*16 = 128000
  int2*     pairs   = (int2*)(ws + 128000);        // 480000*2 = 960000
  float*    fx1     = ws + 1088000;                // 480000 (k4 output)
  float*    s2      = ws + 1568000;                // 480000
  float*    gstats  = ws + 2048000;                // 288: [8x32 BN1 | 32 BN2]
  int*      cursors = (int*)(ws + 2048288);        // 4096
  unsigned* benc    = (unsigned*)(ws + 2052384);   // 750 (encoded bounds)
  // kNN accel structures live in fx1's span until k2 completes (stream-ordered):
  float4*   atoms4s = (float4*)(ws + 1088000);     // 32000 floats
  int*      origid  = (int*)(ws + 1120000);        // 8000

  kB_hist_scan<<<1, 1024, 0, stream>>>(atom_xyz, cursors, gstats, benc);
  kC_scatter_mlp<<<32, 256, 0, stream>>>(atom_xyz, atom_types, Wt1, bt1,
                                         Wt2, bt2, Wt3, bt3, W1, b1,
                                         cursors, atoms4s, origid, benc, tu);
  k2_knn<<<7500, 256, 0, stream>>>(xyz, atoms4s, origid, benc, atom_xyz,
                                   tu, W1, pairs, gstats);
  k4_main<<<1875, 256, 0, stream>>>(pairs, tu, W1, W2, b2, g1, be1,
                                    fx1, s2, gstats);
  k5_final<<<118, 256, 0, stream>>>(fx1, s2, gstats, W3, b3, g2, be2, out);
}

// Round 15
// 215.428 us; speedup vs baseline: 1.0981x; 1.0981x over previous
//
#include <hip/hip_runtime.h>

#define N_PTS   30000
#define M_ATOMS 8000
#define D       16
#define KNN     16
#define NGRP    125           // 8000 / 64 exactly
#define EPS     1e-5f
#define SLOPE   0.2f
#define BN_COUNT 480000.0f    // N_PTS * KNN

typedef unsigned long long ull;

__device__ __forceinline__ float leaky(float x) { return x > 0.f ? x : SLOPE * x; }

// sortable key: strictly monotone bijection float -> u32
__device__ __forceinline__ unsigned fkey(float f) {
  unsigned u = __float_as_uint(f);
  return u ^ ((u & 0x80000000u) ? 0xFFFFFFFFu : 0x80000000u);
}

// ---- DPP wave-min reduction (row_shr:1/2/4/8 -> bcast15 -> bcast31 -> lane63)
#define DPPSTEP32(v, CTRL) {                                                   \
  unsigned t_ = (unsigned)__builtin_amdgcn_update_dpp(-1, (int)(v), CTRL, 0xF, 0xF, false); \
  (v) = t_ < (v) ? t_ : (v); }

__device__ __forceinline__ unsigned wmin32d(unsigned v) {
  DPPSTEP32(v, 0x111); DPPSTEP32(v, 0x112); DPPSTEP32(v, 0x114);
  DPPSTEP32(v, 0x118); DPPSTEP32(v, 0x142); DPPSTEP32(v, 0x143);
  return (unsigned)__builtin_amdgcn_readlane((int)v, 63);   // wave-uniform
}

__device__ __forceinline__ void cswap(ull& a, ull& b) {
  ull mn = a < b ? a : b, mx = a < b ? b : a;
  a = mn; b = mx;
}

__device__ __forceinline__ int morton_cell(float x, float y, float z) {
  int cx = min(max((int)floorf((x + 4.f) * 2.f), 0), 15);
  int cy = min(max((int)floorf((y + 4.f) * 2.f), 0), 15);
  int cz = min(max((int)floorf((z + 4.f) * 2.f), 0), 15);
  int c = 0;
#pragma unroll
  for (int b = 0; b < 4; ++b)
    c |= (((cx>>b)&1) << (3*b)) | (((cy>>b)&1) << (3*b+1)) | (((cz>>b)&1) << (3*b+2));
  return c;
}

// ---------------------------------------------------------------------------
// KZ: zero 4096 histogram bins + 288 gstats
// ---------------------------------------------------------------------------
__global__ void __launch_bounds__(256) kZ_zero(int* __restrict__ bins,
                                               float* __restrict__ gstats) {
  int i = blockIdx.x * 256 + threadIdx.x;
  if (i < 4096) bins[i] = 0;
  else if (i - 4096 < 288) gstats[i - 4096] = 0.f;
}

// ---------------------------------------------------------------------------
// KA: atom MLP -> u' = t@W1+b1, plus global-atomic Morton histogram
// ---------------------------------------------------------------------------
#define LAYER(IN, OUT, W, B)                                        \
  _Pragma("unroll") for (int j = 0; j < 16; ++j) {                  \
    float acc = B[j];                                               \
    _Pragma("unroll") for (int i = 0; i < 16; ++i)                  \
      acc = fmaf(IN[i], W[i*16+j], acc);                            \
    OUT[j] = leaky(acc);                                            \
  }

__global__ void __launch_bounds__(256) kA_mlp_hist(
    const float* __restrict__ atom_xyz, const float* __restrict__ atom_types,
    const float* __restrict__ Wt1, const float* __restrict__ bt1,
    const float* __restrict__ Wt2, const float* __restrict__ bt2,
    const float* __restrict__ Wt3, const float* __restrict__ bt3,
    const float* __restrict__ W1, const float* __restrict__ b1,
    float* __restrict__ tu_out, int* __restrict__ bins) {
  __shared__ float w1[256], w2[256], w3[256], wc[256];
  __shared__ float bb1[16], bb2[16], bb3[16], bbc[16];
  int tid = threadIdx.x;
  w1[tid] = Wt1[tid]; w2[tid] = Wt2[tid]; w3[tid] = Wt3[tid]; wc[tid] = W1[tid];
  if (tid < 16) { bb1[tid] = bt1[tid]; bb2[tid] = bt2[tid];
                  bb3[tid] = bt3[tid]; bbc[tid] = b1[tid]; }
  __syncthreads();
  int m = blockIdx.x * 256 + tid;
  if (m >= M_ATOMS) return;

  // histogram (global atomics; 8000 adds over 4096 bins chip-wide)
  int c = morton_cell(atom_xyz[m*3], atom_xyz[m*3+1], atom_xyz[m*3+2]);
  atomicAdd(&bins[c], 1);

  float u[16], v[16];
  const float4* tp = (const float4*)(atom_types + (size_t)m*16);
  float4 q0 = tp[0], q1 = tp[1], q2 = tp[2], q3 = tp[3];
  u[0]=q0.x; u[1]=q0.y; u[2]=q0.z; u[3]=q0.w;
  u[4]=q1.x; u[5]=q1.y; u[6]=q1.z; u[7]=q1.w;
  u[8]=q2.x; u[9]=q2.y; u[10]=q2.z; u[11]=q2.w;
  u[12]=q3.x; u[13]=q3.y; u[14]=q3.z; u[15]=q3.w;
  LAYER(u, v, w1, bb1);
  LAYER(v, u, w2, bb2);
  LAYER(u, v, w3, bb3);
  float up[16];
#pragma unroll
  for (int j = 0; j < 16; ++j) {
    float acc = bbc[j];
#pragma unroll
    for (int i = 0; i < 16; ++i) acc = fmaf(v[i], wc[i*16+j], acc);
    up[j] = acc;
  }
  float4* op = (float4*)(tu_out + (size_t)m*16);
  op[0] = make_float4(up[0], up[1], up[2], up[3]);
  op[1] = make_float4(up[4], up[5], up[6], up[7]);
  op[2] = make_float4(up[8], up[9], up[10], up[11]);
  op[3] = make_float4(up[12], up[13], up[14], up[15]);
}

// ---------------------------------------------------------------------------
// KB: exclusive scan of 4096 bins -> cursors (1 block, 1024 threads)
// ---------------------------------------------------------------------------
__global__ void __launch_bounds__(1024) kB_scan(
    const int* __restrict__ bins, int* __restrict__ cursors) {
  __shared__ int h0[4096], h1[4096];
  int tid = threadIdx.x;
  for (int i = tid; i < 4096; i += 1024) h0[i] = bins[i];
  __syncthreads();
  int* src = h0; int* dst = h1;
  for (int off = 1; off < 4096; off <<= 1) {
    for (int i = tid; i < 4096; i += 1024) {
      int v = src[i];
      if (i >= off) v += src[i-off];
      dst[i] = v;
    }
    __syncthreads();
    int* t = src; src = dst; dst = t;
  }
  for (int i = tid; i < 4096; i += 1024) cursors[i] = i ? src[i-1] : 0;
}

// ---------------------------------------------------------------------------
// KC: scatter atoms to Morton order via global cursor atomics
// ---------------------------------------------------------------------------
__global__ void __launch_bounds__(256) kC_scatter(
    const float* __restrict__ atom_xyz, int* __restrict__ cursors,
    float4* __restrict__ atoms4s, int* __restrict__ origid) {
  int m = blockIdx.x * 256 + threadIdx.x;
  if (m >= M_ATOMS) return;
  float x = atom_xyz[m*3], y = atom_xyz[m*3+1], z = atom_xyz[m*3+2];
  int c = morton_cell(x, y, z);
  int pos = atomicAdd(&cursors[c], 1);
  atoms4s[pos] = make_float4(x, y, z, fmaf(x,x, fmaf(y,y, z*z)));
  origid[pos] = m;
}

// ---------------------------------------------------------------------------
// K_BOUNDS: AABB per group of 64 sorted atoms. One wave per group.
// ---------------------------------------------------------------------------
__global__ void __launch_bounds__(256) k_bounds(
    const float4* __restrict__ atoms4s, float4* __restrict__ bounds) {
  int lane = threadIdx.x & 63;
  int g = blockIdx.x * 4 + (threadIdx.x >> 6);
  if (g >= NGRP) return;
  float4 a = atoms4s[(g << 6) + lane];
  float mnx=a.x, mny=a.y, mnz=a.z, mxx=a.x, mxy=a.y, mxz=a.z;
#pragma unroll
  for (int off = 32; off; off >>= 1) {
    mnx = fminf(mnx, __shfl_xor(mnx, off, 64));
    mny = fminf(mny, __shfl_xor(mny, off, 64));
    mnz = fminf(mnz, __shfl_xor(mnz, off, 64));
    mxx = fmaxf(mxx, __shfl_xor(mxx, off, 64));
    mxy = fmaxf(mxy, __shfl_xor(mxy, off, 64));
    mxz = fmaxf(mxz, __shfl_xor(mxz, off, 64));
  }
  if (lane == 0) {
    bounds[2*g]   = make_float4(mnx, mny, mnz, 0.f);
    bounds[2*g+1] = make_float4(mxx, mxy, mxz, 0.f);
  }
}

// ---------------------------------------------------------------------------
// K2 v7 (R10-proven, measured 72 us): exact 16-NN + fused BN1 stats.
// ---------------------------------------------------------------------------
__global__ void __launch_bounds__(256) k2_knn(
    const float* __restrict__ xyz, const float4* __restrict__ atoms4s,
    const int* __restrict__ origid, const float4* __restrict__ bounds,
    const float* __restrict__ atom_xyz, const float* __restrict__ tu,
    const float* __restrict__ W1,
    int2* __restrict__ pairs, float* __restrict__ gstats) {
  __shared__ float sbuf[4*16*20];
  int tid = threadIdx.x;
  int lane = tid & 63;
  int wid = tid >> 6;
  int n = blockIdx.x * 4 + wid;              // 30000 = 7500*4 exactly

  float px = xyz[n*3+0], py = xyz[n*3+1], pz = xyz[n*3+2];
  float x2 = fmaf(px,px, fmaf(py,py, pz*pz));

  unsigned ea, eb = 0xFFFFFFFFu;
  {
    int g = lane;
    float4 mn = bounds[2*g], mx = bounds[2*g+1];
    float dx = fmaxf(fmaxf(mn.x - px, px - mx.x), 0.f);
    float dy = fmaxf(fmaxf(mn.y - py, py - mx.y), 0.f);
    float dz = fmaxf(fmaxf(mn.z - pz, pz - mx.z), 0.f);
    float lb = fmaf(dx,dx, fmaf(dy,dy, dz*dz)) * 0.999f - 1e-4f;
    ea = (fkey(lb) & 0xFFFFFF00u) | (unsigned)g;
  }
  if (lane + 64 < NGRP) {
    int g = lane + 64;
    float4 mn = bounds[2*g], mx = bounds[2*g+1];
    float dx = fmaxf(fmaxf(mn.x - px, px - mx.x), 0.f);
    float dy = fmaxf(fmaxf(mn.y - py, py - mx.y), 0.f);
    float dz = fmaxf(fmaxf(mn.z - pz, pz - mx.z), 0.f);
    float lb = fmaf(dx,dx, fmaf(dy,dy, dz*dz)) * 0.999f - 1e-4f;
    eb = (fkey(lb) & 0xFFFFFF00u) | (unsigned)g;
  }
  unsigned cur = ea < eb ? ea : eb;
  unsigned bak = ea < eb ? eb : ea;

  int gs[4];
#pragma unroll
  for (int r = 0; r < 4; ++r) {
    unsigned m = wmin32d(cur);
    bool own = (cur == m);
    cur = own ? bak : cur;
    bak = own ? 0xFFFFFFFFu : bak;
    gs[r] = (int)(m & 0xFFu);
  }

  float4 A[4]; int OI[4];
#pragma unroll
  for (int r = 0; r < 4; ++r) {
    int base = gs[r] << 6;
    A[r]  = atoms4s[base + lane];
    OI[r] = origid [base + lane];
  }
  ull E[4];
#pragma unroll
  for (int r = 0; r < 4; ++r) {
    float dotp = fmaf(px,A[r].x, fmaf(py,A[r].y, pz*A[r].z));
    float d2 = (x2 + A[r].w) - 2.f*dotp;     // reference expansion metric
    E[r] = ((ull)fkey(d2) << 32) | (unsigned)OI[r];
  }
  cswap(E[0],E[1]); cswap(E[2],E[3]); cswap(E[0],E[2]);
  cswap(E[1],E[3]); cswap(E[1],E[2]);
  unsigned cf0 = (unsigned)(E[0] >> 32), ci0 = (unsigned)E[0];
  unsigned cf1 = (unsigned)(E[1] >> 32), ci1 = (unsigned)E[1];
  unsigned cf2 = (unsigned)(E[2] >> 32), ci2 = (unsigned)E[2];
  unsigned cf3 = (unsigned)(E[3] >> 32), ci3 = (unsigned)E[3];

  ull res = ~0ull;
  unsigned mf = 0, mi = 0;
  for (int r = 0; r < KNN; ++r) {
    mf = wmin32d(cf0);
    ull ball = __ballot(cf0 == mf);
    if (__popcll(ball) == 1) {
      int srcl = (int)(__ffsll(ball) - 1);
      mi = (unsigned)__builtin_amdgcn_readlane((int)ci0, srcl);
    } else {
      unsigned cand = (cf0 == mf) ? ci0 : 0xFFFFFFFFu;
      mi = wmin32d(cand);
    }
    bool own = (cf0 == mf) && (ci0 == mi);
    if (lane == r) res = (((ull)mf) << 32) | mi;
    cf0 = own ? cf1 : cf0; cf1 = own ? cf2 : cf1;
    cf2 = own ? cf3 : cf2; cf3 = own ? 0xFFFFFFFFu : cf3;
    ci0 = own ? ci1 : ci0; ci1 = own ? ci2 : ci1;
    ci2 = own ? ci3 : ci2; ci3 = own ? 0xFFFFFFFFu : ci3;
  }
  ull lv = res;
  ull thresh = (((ull)mf) << 32) | mi;

  for (int it = 0; it < NGRP - 4; ++it) {
    unsigned m = wmin32d(cur);
    if ((m & 0xFFFFFF00u) >= (unsigned)(thresh >> 32)) break;
    bool own = (cur == m);
    cur = own ? bak : cur;
    bak = own ? 0xFFFFFFFFu : bak;
    int base = (int)(m & 0xFFu) << 6;

    float4 a = atoms4s[base + lane];
    int oi2 = origid[base + lane];
    float dotp = fmaf(px,a.x, fmaf(py,a.y, pz*a.z));
    float d2 = (x2 + a.w) - 2.f*dotp;
    ull key = ((ull)fkey(d2) << 32) | (unsigned)oi2;

    ull mk = __ballot(key < thresh);
    while (mk) {
      int src = (int)(__ffsll(mk) - 1);
      mk &= mk - 1;
      unsigned klo = (unsigned)__builtin_amdgcn_readlane((int)(unsigned)key, src);
      unsigned khi = (unsigned)__builtin_amdgcn_readlane((int)(unsigned)(key >> 32), src);
      ull kc = ((ull)khi << 32) | klo;
      if (kc < thresh) {
        bool ins = (lane < KNN) && (kc < lv);
        unsigned pvlo = (unsigned)__builtin_amdgcn_update_dpp(0, (int)(unsigned)lv,        0x111, 0xF, 0xF, false);
        unsigned pvhi = (unsigned)__builtin_amdgcn_update_dpp(0, (int)(unsigned)(lv>>32), 0x111, 0xF, 0xF, false);
        int pins      =           __builtin_amdgcn_update_dpp(0, ins ? 1 : 0,              0x111, 0xF, 0xF, false);
        if (ins) lv = pins ? (((ull)pvhi << 32) | pvlo) : kc;
        unsigned tlo = (unsigned)__builtin_amdgcn_readlane((int)(unsigned)lv, KNN-1);
        unsigned thi = (unsigned)__builtin_amdgcn_readlane((int)(unsigned)(lv >> 32), KNN-1);
        thresh = ((ull)thi << 32) | tlo;
      }
    }
  }

  int oi = (int)(unsigned)(lv & 0xFFFFFFFFull);
  float iv = 0.f;
  if (lane < KNN) {
    float bx = atom_xyz[oi*3+0], by = atom_xyz[oi*3+1], bz = atom_xyz[oi*3+2];
    float dx = px - bx, dy = py - by, dz = pz - bz;
    float dd = fmaf(dx,dx, fmaf(dy,dy, dz*dz));    // exact recompute (reference)
    iv = 1.f / dd;
    pairs[n*KNN + lane] = make_int2(oi, __float_as_int(iv));

    const float4* up4 = (const float4*)(tu + (size_t)oi*16);
    float4 u0 = up4[0], u1 = up4[1], u2 = up4[2], u3 = up4[3];
    float4* row = (float4*)&sbuf[(wid*16 + lane)*20];
    float4 w;
    w.x = leaky(fmaf(iv, W1[256+ 0], u0.x)); w.y = leaky(fmaf(iv, W1[256+ 1], u0.y));
    w.z = leaky(fmaf(iv, W1[256+ 2], u0.z)); w.w = leaky(fmaf(iv, W1[256+ 3], u0.w));
    row[0] = w;
    w.x = leaky(fmaf(iv, W1[256+ 4], u1.x)); w.y = leaky(fmaf(iv, W1[256+ 5], u1.y));
    w.z = leaky(fmaf(iv, W1[256+ 6], u1.z)); w.w = leaky(fmaf(iv, W1[256+ 7], u1.w));
    row[1] = w;
    w.x = leaky(fmaf(iv, W1[256+ 8], u2.x)); w.y = leaky(fmaf(iv, W1[256+ 9], u2.y));
    w.z = leaky(fmaf(iv, W1[256+10], u2.z)); w.w = leaky(fmaf(iv, W1[256+11], u2.w));
    row[2] = w;
    w.x = leaky(fmaf(iv, W1[256+12], u3.x)); w.y = leaky(fmaf(iv, W1[256+13], u3.y));
    w.z = leaky(fmaf(iv, W1[256+14], u3.z)); w.w = leaky(fmaf(iv, W1[256+15], u3.w));
    row[3] = w;
  }
  __syncthreads();
  {
    int ch = tid & 15, grp = tid >> 4;
    float S = 0.f, Q = 0.f;
#pragma unroll
    for (int i = 0; i < 4; ++i) {
      float v = sbuf[(grp*4 + i)*20 + ch];
      S += v; Q += v*v;
    }
    __syncthreads();
    sbuf[grp*20 + ch] = S;
    sbuf[400 + grp*20 + ch] = Q;
  }
  __syncthreads();
  if (tid < 32) {
    int ch = tid & 15;
    int off = (tid < 16) ? 0 : 400;
    float s = 0.f;
#pragma unroll
    for (int g = 0; g < 16; ++g) s += sbuf[off + g*20 + ch];
    atomicAdd(&gstats[(blockIdx.x & 7)*32 + tid], s);
  }
}

// ---------------------------------------------------------------------------
// a1 row from precomputed u': a1 = leaky(u'[idx] + iv * wiv)
// ---------------------------------------------------------------------------
__device__ __forceinline__ void a1_row(const float* __restrict__ tu, int idx,
                                       float iv, const float* wiv, float* a) {
  const float4* up = (const float4*)(tu + (size_t)idx*16);
  float4 r0 = up[0], r1 = up[1], r2 = up[2], r3 = up[3];
  float u[16];
  u[0]=r0.x; u[1]=r0.y; u[2]=r0.z; u[3]=r0.w;
  u[4]=r1.x; u[5]=r1.y; u[6]=r1.z; u[7]=r1.w;
  u[8]=r2.x; u[9]=r2.y; u[10]=r2.z; u[11]=r2.w;
  u[12]=r3.x; u[13]=r3.y; u[14]=r3.z; u[15]=r3.w;
#pragma unroll
  for (int j = 0; j < 16; ++j) a[j] = leaky(fmaf(iv, wiv[j], u[j]));
}

// ---------------------------------------------------------------------------
// K4 (R10-proven): a1, BN1 -> h, fx1; a2, s2; BN2 stats.
// ---------------------------------------------------------------------------
__global__ void __launch_bounds__(256, 4) k4_main(
    const int2* __restrict__ pairs, const float* __restrict__ tu,
    const float* __restrict__ W1,
    const float* __restrict__ W2, const float* __restrict__ b2,
    const float* __restrict__ g1, const float* __restrict__ be1,
    float* __restrict__ fx1_out, float* __restrict__ s2_out,
    float* __restrict__ gstats) {
  __shared__ float wiv[16], w2s[256], b2s[16];
  __shared__ float sc1[16], sh1[16];
  __shared__ float buf[16*16*17];
  int tid = threadIdx.x;
  w2s[tid] = W2[tid];
  if (tid < 16) { wiv[tid] = W1[256 + tid]; b2s[tid] = b2[tid]; }
  if (tid < 16) {
    float s1 = 0.f, q1 = 0.f;
#pragma unroll
    for (int c = 0; c < 8; ++c) { s1 += gstats[c*32 + tid]; q1 += gstats[c*32 + 16 + tid]; }
    float mean = s1 * (1.f/BN_COUNT);
    float var  = q1 * (1.f/BN_COUNT) - mean*mean;
    float sC = g1[tid] / sqrtf(var + EPS);
    sc1[tid] = sC;
    sh1[tid] = be1[tid] - mean * sC;
  }
  __syncthreads();

  int g = blockIdx.x * 256 + tid;
  int p = tid >> 4, k = tid & 15;
  int2 pr = pairs[g];
  int idx = pr.x;
  float iv = __int_as_float(pr.y);
  float h[16], a2[16];
  a1_row(tu, idx, iv, wiv, h);
#pragma unroll
  for (int j = 0; j < 16; ++j) h[j] = fmaf(h[j], sc1[j], sh1[j]);
#pragma unroll
  for (int j = 0; j < 16; ++j) {
    float accj = b2s[j];
#pragma unroll
    for (int i = 0; i < 16; ++i) accj = fmaf(h[i], w2s[i*16+j], accj);
    a2[j] = leaky(accj);
  }

  float* myrow = &buf[(p*16 + k)*17];
  int p2 = tid >> 4, j2 = tid & 15;
#pragma unroll
  for (int j = 0; j < 16; ++j) myrow[j] = h[j];
  __syncthreads();
  {
    float s = 0.f;
#pragma unroll
    for (int kk = 0; kk < 16; ++kk) s += buf[(p2*16+kk)*17 + j2];
    fx1_out[(size_t)blockIdx.x*256 + tid] = s;
  }
  __syncthreads();
#pragma unroll
  for (int j = 0; j < 16; ++j) myrow[j] = a2[j];
  __syncthreads();
  float s2v = 0.f;
#pragma unroll
  for (int kk = 0; kk < 16; ++kk) s2v += buf[(p2*16+kk)*17 + j2];
  s2_out[(size_t)blockIdx.x*256 + tid] = s2v;
  __syncthreads();
#pragma unroll
  for (int j = 0; j < 16; ++j) myrow[j] = a2[j]*a2[j];
  __syncthreads();
  float q2v = 0.f;
#pragma unroll
  for (int kk = 0; kk < 16; ++kk) q2v += buf[(p2*16+kk)*17 + j2];
  __syncthreads();
  buf[p2*17 + j2] = s2v;
  buf[289 + p2*17 + j2] = q2v;
  __syncthreads();
  if (tid < 16) {
    float t1 = 0.f, t2 = 0.f;
#pragma unroll
    for (int pp = 0; pp < 16; ++pp) { t1 += buf[pp*17 + tid]; t2 += buf[289 + pp*17 + tid]; }
    atomicAdd(&gstats[256 + tid], t1);
    atomicAdd(&gstats[272 + tid], t2);
  }
}

// ---------------------------------------------------------------------------
// K5 (R10-proven): fx2 = sc2*s2 + 16*sh2 ; out = [fx1,fx2]@W3 + b3
// ---------------------------------------------------------------------------
__global__ void __launch_bounds__(256) k5_final(
    const float* __restrict__ fx1_in, const float* __restrict__ s2_in,
    const float* __restrict__ gstats,
    const float* __restrict__ W3, const float* __restrict__ b3,
    const float* __restrict__ g2, const float* __restrict__ be2,
    float* __restrict__ out) {
  __shared__ float w[512], bb[16], sc2[16], sh2[16];
  int tid = threadIdx.x;
  w[tid] = W3[tid]; w[256+tid] = W3[256+tid];
  if (tid < 16) {
    bb[tid] = b3[tid];
    float mean = gstats[256+tid] * (1.f/BN_COUNT);
    float var  = gstats[272+tid] * (1.f/BN_COUNT) - mean*mean;
    float s = g2[tid] / sqrtf(var + EPS);
    sc2[tid] = s;
    sh2[tid] = be2[tid] - mean * s;
  }
  __syncthreads();
  int n = blockIdx.x * 256 + tid;
  if (n >= N_PTS) return;

  const float4* f1p = (const float4*)(fx1_in + (size_t)n*16);
  const float4* f2p = (const float4*)(s2_in  + (size_t)n*16);
  float4 x0=f1p[0], x1=f1p[1], x2=f1p[2], x3=f1p[3];
  float4 y0=f2p[0], y1=f2p[1], y2=f2p[2], y3=f2p[3];
  float f1[16] = {x0.x,x0.y,x0.z,x0.w, x1.x,x1.y,x1.z,x1.w,
                  x2.x,x2.y,x2.z,x2.w, x3.x,x3.y,x3.z,x3.w};
  float f2[16] = {y0.x,y0.y,y0.z,y0.w, y1.x,y1.y,y1.z,y1.w,
                  y2.x,y2.y,y2.z,y2.w, y3.x,y3.y,y3.z,y3.w};
#pragma unroll
  for (int i = 0; i < 16; ++i) f2[i] = fmaf(sc2[i], f2[i], 16.f * sh2[i]);

  float4* op = (float4*)(out + (size_t)n*16);
  float o[16];
#pragma unroll
  for (int j = 0; j < 16; ++j) {
    float accj = bb[j];
#pragma unroll
    for (int i = 0; i < 16; ++i) accj = fmaf(f1[i], w[i*16+j], accj);
#pragma unroll
    for (int i = 0; i < 16; ++i) accj = fmaf(f2[i], w[(16+i)*16+j], accj);
    o[j] = accj;
  }
  op[0] = make_float4(o[0], o[1], o[2], o[3]);
  op[1] = make_float4(o[4], o[5], o[6], o[7]);
  op[2] = make_float4(o[8], o[9], o[10], o[11]);
  op[3] = make_float4(o[12], o[13], o[14], o[15]);
}

// ---------------------------------------------------------------------------
extern "C" void kernel_launch(void* const* d_in, const int* in_sizes, int n_in,
                              void* d_out, int out_size, void* d_ws, size_t ws_size,
                              hipStream_t stream) {
  const float* xyz        = (const float*)d_in[0];
  const float* atom_xyz   = (const float*)d_in[1];
  const float* atom_types = (const float*)d_in[2];
  const float* Wt1 = (const float*)d_in[3];  const float* bt1 = (const float*)d_in[4];
  const float* Wt2 = (const float*)d_in[5];  const float* bt2 = (const float*)d_in[6];
  const float* Wt3 = (const float*)d_in[7];  const float* bt3 = (const float*)d_in[8];
  const float* W1  = (const float*)d_in[9];  const float* b1  = (const float*)d_in[10];
  const float* W2  = (const float*)d_in[11]; const float* b2  = (const float*)d_in[12];
  const float* W3  = (const float*)d_in[13]; const float* b3  = (const float*)d_in[14];
  const float* g1  = (const float*)d_in[15]; const float* be1 = (const float*)d_in[16];
  const float* g2  = (const float*)d_in[17]; const float* be2 = (const float*)d_in[18];
  float* out = (float*)d_out;

  float* ws = (float*)d_ws;
  float*    tu      = ws;                          // 8000*16 = 128000
  int2*     pairs   = (int2*)(ws + 128000);        // 480000*2 = 960000
  float*    fx1     = ws + 1088000;                // 480000 (k4 output)
  float*    s2      = ws + 1568000;                // 480000
  float*    gstats  = ws + 2048000;                // 288: [8x32 BN1 | 32 BN2]
  int*      bins    = (int*)(ws + 2048288);        // 4096
  int*      cursors = (int*)(ws + 2052384);        // 4096
  float4*   bounds  = (float4*)(ws + 2056480);     // 250 float4
  // kNN accel structures live in fx1's span until k2 completes (stream-ordered):
  float4*   atoms4s = (float4*)(ws + 1088000);     // 32000 floats
  int*      origid  = (int*)(ws + 1120000);        // 8000

  kZ_zero<<<18, 256, 0, stream>>>(bins, gstats);
  kA_mlp_hist<<<32, 256, 0, stream>>>(atom_xyz, atom_types, Wt1, bt1, Wt2, bt2,
                                      Wt3, bt3, W1, b1, tu, bins);
  kB_scan<<<1, 1024, 0, stream>>>(bins, cursors);
  kC_scatter<<<32, 256, 0, stream>>>(atom_xyz, cursors, atoms4s, origid);
  k_bounds<<<32, 256, 0, stream>>>(atoms4s, bounds);
  k2_knn<<<7500, 256, 0, stream>>>(xyz, atoms4s, origid, bounds, atom_xyz,
                                   tu, W1, pairs, gstats);
  k4_main<<<1875, 256, 0, stream>>>(pairs, tu, W1, W2, b2, g1, be1,
                                    fx1, s2, gstats);
  k5_final<<<118, 256, 0, stream>>>(fx1, s2, gstats, W3, b3, g2, be2, out);
}